// Round 4
// baseline (427.467 us; speedup 1.0000x reference)
//
#include <hip/hip_runtime.h>
#include <hip/hip_bf16.h>

// MultiHeadAttention fused forward for MI355X (gfx950).
// B=2, S=2048, D=1024, H=16, DH=64. Outputs: out [B,S,D] fp32, attn [B,H,S,S] fp32.
static constexpr int cB = 2, cS = 2048, cD = 1024, cH = 16, cDH = 64;

typedef __attribute__((ext_vector_type(4))) float f32x4;
typedef __attribute__((ext_vector_type(8))) short s16x8;
typedef unsigned long long u64;
typedef unsigned short u16;

__device__ inline f32x4 mfma16(s16x8 a, s16x8 b, f32x4 c) {
  return __builtin_amdgcn_mfma_f32_16x16x32_bf16(a, b, c, 0, 0, 0);
}

// fp32 -> bf16 round-to-nearest-even
__device__ inline u16 f2bf(float x) {
  unsigned u = __float_as_uint(x);
  u += 0x7FFFu + ((u >> 16) & 1u);
  return (u16)(u >> 16);
}

__device__ inline f32x4 zero4() { f32x4 z; z[0] = z[1] = z[2] = z[3] = 0.f; return z; }

// global -> LDS direct copy, 16 B per lane. dst is the wave-uniform base; HW
// adds lane*16. src is per-lane.
__device__ inline void gload16(const void* src, void* dst) {
  __builtin_amdgcn_global_load_lds((const __attribute__((address_space(1))) void*)src,
                                   (__attribute__((address_space(3))) void*)dst, 16, 0, 0);
}

// Fragment k-map (A and B identical per MFMA, bijective per 16-lane group):
//   QK^T: dh = c*32 + g*8 + e (contiguous 8)
//   PV:   k  = c*32 + h*16 + 4*g + r, frag elem e = h*4 + r
// Tiles in LDS are [rows][8 chunks of 16B] with chunk XOR-swizzle: global chunk q
// of row r sits at LDS chunk q ^ (r&7), staged via inverse-swizzled global source.

// ---------------- W transpose + bf16 convert: W[k][n] fp32 -> Wt[n][k] bf16 ----
__global__ __launch_bounds__(256) void wt_kernel(const float* __restrict__ W,
                                                 u16* __restrict__ Wt) {
  __shared__ float tile[32][33];
  int tx = threadIdx.x, ty = threadIdx.y;
  int r0 = blockIdx.y * 32, c0 = blockIdx.x * 32;
  for (int i = ty; i < 32; i += 8)
    tile[i][tx] = W[(size_t)(r0 + i) * cD + c0 + tx];
  __syncthreads();
  for (int i = ty; i < 32; i += 8)
    Wt[(size_t)(c0 + i) * cD + r0 + tx] = f2bf(tile[tx][i]);
}

// ---------------- mask nonzero bitmap: flag per (b, 64-row qtile, 64-col ktile) --
__global__ __launch_bounds__(256) void maskflag_kernel(const float* __restrict__ mask,
                                                       unsigned char* __restrict__ flags) {
  int blk = blockIdx.x;                       // b*1024 + qt*32 + kt
  int b = blk >> 10, qt = (blk >> 5) & 31, kt = blk & 31;
  int t = threadIdx.x;
  int r = t >> 2, c0 = (t & 3) * 16;
  const float4* p = (const float4*)(mask + ((size_t)b * cS + qt * 64 + r) * cS + kt * 64 + c0);
  int any = 0;
  for (int j = 0; j < 4; ++j) {
    float4 v = p[j];
    any |= (v.x != 0.f) | (v.y != 0.f) | (v.z != 0.f) | (v.w != 0.f);
  }
  __shared__ int sred;
  if (t == 0) sred = 0;
  __syncthreads();
  if (any) atomicOr(&sred, 1);
  __syncthreads();
  if (t == 0) flags[blk] = (unsigned char)sred;
}

// ---------------- 128x128x64 GEMM, 4 waves, 4x4 frags/wave -----------------------
template<bool AFP32, bool OUTF32>
__global__ __launch_bounds__(256) void gemm128(const void* __restrict__ Ap,
                                               const u16* __restrict__ Bt,
                                               const float* __restrict__ bias,
                                               void* __restrict__ outp,
                                               float scale, int vt_mode) {
  __shared__ __attribute__((aligned(16))) u16 As[128 * 64];
  __shared__ __attribute__((aligned(16))) u16 Bs[128 * 64];
  int t = threadIdx.x;
  int w = t >> 6, l = t & 63, g = l >> 4, li = l & 15;
  int bm = blockIdx.x & 31, bn = blockIdx.x >> 5;
  int m0 = bm * 128, n0 = bn * 128;
  int wr = w >> 1, wc = w & 1;

  f32x4 acc[4][4];
  for (int i = 0; i < 4; ++i)
    for (int j = 0; j < 4; ++j) acc[i][j] = zero4();

  for (int kk = 0; kk < cD; kk += 64) {
    if (AFP32) {
      const float* X = (const float*)Ap;
      int ar = t >> 1, ak0 = (t & 1) * 32;
      const float* asrc = X + (size_t)(m0 + ar) * cD + kk + ak0;
      int sw = ar & 7;
      for (int j = 0; j < 4; ++j) {
        float4 x0 = ((const float4*)asrc)[2 * j];
        float4 x1 = ((const float4*)asrc)[2 * j + 1];
        union { s16x8 v; u16 h[8]; } s;
        s.h[0] = f2bf(x0.x); s.h[1] = f2bf(x0.y); s.h[2] = f2bf(x0.z); s.h[3] = f2bf(x0.w);
        s.h[4] = f2bf(x1.x); s.h[5] = f2bf(x1.y); s.h[6] = f2bf(x1.z); s.h[7] = f2bf(x1.w);
        int chunk = (ak0 >> 3) + j;
        *(s16x8*)&As[ar * 64 + ((chunk ^ sw) * 8)] = s.v;
      }
    } else {
      const u16* X = (const u16*)Ap;
      for (int is = 0; is < 4; ++is) {
        int row = w * 32 + is * 8 + (l >> 3);
        int chunk = l & 7;
        const u16* src = X + (size_t)(m0 + row) * cD + kk + ((chunk ^ (row & 7)) * 8);
        gload16(src, &As[(w * 32 + is * 8) * 64]);
      }
    }
    for (int is = 0; is < 4; ++is) {
      int row = w * 32 + is * 8 + (l >> 3);
      int chunk = l & 7;
      const u16* src = Bt + (size_t)(n0 + row) * cD + kk + ((chunk ^ (row & 7)) * 8);
      gload16(src, &Bs[(w * 32 + is * 8) * 64]);
    }
    __syncthreads();
    for (int c = 0; c < 2; ++c) {
      s16x8 af[4], bf[4];
      for (int mi = 0; mi < 4; ++mi) {
        int r = wr * 64 + mi * 16 + li;
        af[mi] = *(const s16x8*)&As[r * 64 + (((c * 4 + g) ^ (r & 7)) * 8)];
      }
      for (int ni = 0; ni < 4; ++ni) {
        int r = wc * 64 + ni * 16 + li;
        bf[ni] = *(const s16x8*)&Bs[r * 64 + (((c * 4 + g) ^ (r & 7)) * 8)];
      }
      for (int mi = 0; mi < 4; ++mi)
        for (int ni = 0; ni < 4; ++ni)
          acc[mi][ni] = mfma16(af[mi], bf[ni], acc[mi][ni]);
    }
    __syncthreads();
  }

  for (int ni = 0; ni < 4; ++ni) {
    int n = n0 + wc * 64 + ni * 16 + li;
    float bv = bias[n];
    for (int mi = 0; mi < 4; ++mi) {
      for (int r = 0; r < 4; ++r) {
        int m = m0 + wr * 64 + mi * 16 + g * 4 + r;
        float val = acc[mi][ni][r] + bv;
        if (OUTF32) {
          ((float*)outp)[(size_t)m * cD + n] = val;
        } else {
          val *= scale;
          int b = m >> 11, s = m & 2047;
          int h = n >> 6, d = n & 63;
          size_t idx = vt_mode ? ((size_t)(b * cH + h) * cDH + d) * cS + s
                               : ((size_t)(b * cH + h) * cS + s) * cDH + d;
          ((u16*)outp)[idx] = f2bf(val);
        }
      }
    }
  }
}

// ---------------- fused attention ---------------------------------------------
// Grid: B*H*(S/64) = 1024 blocks, 256 threads (4 waves, 16 q-rows each).
// Swapped QK^T: mfma(K, Q) so lane li owns q-row li; k 4-contiguous per acc quad.
// Pass A: rowsum of exp. Pass B: recompute, write normalized attn (float4), PV
// with in-register P. Both passes double-buffer K/V with prefetch-before-compute.
__global__ __launch_bounds__(256, 3) void attn_kernel(const u16* __restrict__ Q,
                                                      const u16* __restrict__ K,
                                                      const u16* __restrict__ Vt,
                                                      const float* __restrict__ mask,
                                                      const unsigned char* __restrict__ flags,
                                                      float* __restrict__ attn,
                                                      u16* __restrict__ ctx) {
  __shared__ __attribute__((aligned(16))) u16 Kl[2][64 * 64];
  __shared__ __attribute__((aligned(16))) u16 Vl[2][64 * 64];
  int t = threadIdx.x;
  int w = t >> 6, l = t & 63, g = l >> 4, li = l & 15;
  int blk = blockIdx.x;
  int bh = blk >> 5, qt = blk & 31;
  int b = bh >> 4;
  int qbase = qt * 64;
  const u16* Qh = Q + (size_t)bh * cS * cDH;
  const u16* Kh = K + (size_t)bh * cS * cDH;
  const u16* Vh = Vt + (size_t)bh * cDH * cS;
  const unsigned char* fl = flags + (b << 10) + qt * 32;

  // Q fragments (Q pre-scaled by 1/8). Used as the MFMA B operand.
  s16x8 qf[2];
  {
    const u16* qp = Qh + (size_t)(qbase + w * 16 + li) * cDH;
    qf[0] = *(const s16x8*)(qp + 8 * g);
    qf[1] = *(const s16x8*)(qp + 32 + 8 * g);
  }
  int srow8 = l >> 3, schunk = l & 7;
  int q_lane = qbase + w * 16 + li;   // this lane's q-row (swapped layout)

  // ---- Pass A: row sums of exp(logits) ----
  float racc = 0.f;
  for (int is = 0; is < 2; ++is) {
    int row = w * 16 + is * 8 + srow8;
    gload16(Kh + (size_t)row * cDH + ((schunk ^ (row & 7)) * 8), &Kl[0][(w * 16 + is * 8) * 64]);
  }
  __syncthreads();
  int cur = 0;
  for (int kt = 0; kt < 32; ++kt) {
    if (kt + 1 < 32) {
      for (int is = 0; is < 2; ++is) {
        int row = w * 16 + is * 8 + srow8;
        gload16(Kh + (size_t)((kt + 1) * 64 + row) * cDH + ((schunk ^ (row & 7)) * 8),
                &Kl[cur ^ 1][(w * 16 + is * 8) * 64]);
      }
    }
    f32x4 acc[4];
    for (int mt = 0; mt < 4; ++mt) acc[mt] = zero4();
    for (int c = 0; c < 2; ++c)
      for (int mt = 0; mt < 4; ++mt) {
        int r = mt * 16 + li;
        s16x8 kf = *(const s16x8*)&Kl[cur][r * 64 + (((c * 4 + g) ^ (r & 7)) * 8)];
        acc[mt] = mfma16(kf, qf[c], acc[mt]);
      }
    bool um = fl[kt] != 0;
    for (int mt = 0; mt < 4; ++mt)
      for (int r = 0; r < 4; ++r) {
        float lv = acc[mt][r];
        if (um) lv += mask[((size_t)b * cS + q_lane) * cS + kt * 64 + mt * 16 + 4 * g + r] * -1e9f;
        racc += __expf(lv);
      }
    __syncthreads();
    cur ^= 1;
  }
  racc += __shfl_xor(racc, 16, 64);
  racc += __shfl_xor(racc, 32, 64);
  float rs = 1.f / racc;   // inverse denominator for q-row q_lane

  // ---- Pass B: attn write + PV ----
  f32x4 cacc[4];
  for (int dt = 0; dt < 4; ++dt) cacc[dt] = zero4();
  float* attn_row = attn + (size_t)bh * cS * cS + (size_t)q_lane * cS;
  for (int is = 0; is < 2; ++is) {
    int row = w * 16 + is * 8 + srow8;
    gload16(Kh + (size_t)row * cDH + ((schunk ^ (row & 7)) * 8), &Kl[0][(w * 16 + is * 8) * 64]);
    gload16(Vh + (size_t)row * cS + ((schunk ^ (row & 7)) * 8), &Vl[0][(w * 16 + is * 8) * 64]);
  }
  __syncthreads();
  cur = 0;
  for (int kt = 0; kt < 32; ++kt) {
    if (kt + 1 < 32) {
      for (int is = 0; is < 2; ++is) {
        int row = w * 16 + is * 8 + srow8;
        gload16(Kh + (size_t)((kt + 1) * 64 + row) * cDH + ((schunk ^ (row & 7)) * 8),
                &Kl[cur ^ 1][(w * 16 + is * 8) * 64]);
        gload16(Vh + (size_t)row * cS + (kt + 1) * 64 + ((schunk ^ (row & 7)) * 8),
                &Vl[cur ^ 1][(w * 16 + is * 8) * 64]);
      }
    }
    f32x4 acc[4];
    for (int mt = 0; mt < 4; ++mt) acc[mt] = zero4();
    for (int c = 0; c < 2; ++c)
      for (int mt = 0; mt < 4; ++mt) {
        int r = mt * 16 + li;
        s16x8 kf = *(const s16x8*)&Kl[cur][r * 64 + (((c * 4 + g) ^ (r & 7)) * 8)];
        acc[mt] = mfma16(kf, qf[c], acc[mt]);
      }
    bool um = fl[kt] != 0;
    // exp + normalize: store attn as float4, keep bf16 P in registers for PV
    s16x8 pa[2];
    for (int c = 0; c < 2; ++c) {
      union { s16x8 v; u16 h[8]; } pk;
      for (int hh = 0; hh < 2; ++hh) {
        int mt = c * 2 + hh;
        f32x4 pv;
        for (int r = 0; r < 4; ++r) {
          float lv = acc[mt][r];
          if (um) lv += mask[((size_t)b * cS + q_lane) * cS + kt * 64 + mt * 16 + 4 * g + r] * -1e9f;
          float p = __expf(lv) * rs;
          pv[r] = p;
          pk.h[hh * 4 + r] = f2bf(p);
        }
        *(f32x4*)(attn_row + kt * 64 + mt * 16 + 4 * g) = pv;
      }
      pa[c] = pk.v;
    }
    // PV: A = P (in registers, q=li), B = V fragments matching the same k-map
    for (int c = 0; c < 2; ++c) {
      for (int dt = 0; dt < 4; ++dt) {
        int row = dt * 16 + li;
        const u16* rb = &Vl[cur][row * 64];
        int o0 = (((c * 4 + 0 + (g >> 1)) ^ (li & 7)) * 8) + (g & 1) * 4;
        int o1 = (((c * 4 + 2 + (g >> 1)) ^ (li & 7)) * 8) + (g & 1) * 4;
        union { s16x8 v; u64 qq[2]; } vf;
        vf.qq[0] = *(const u64*)(rb + o0);
        vf.qq[1] = *(const u64*)(rb + o1);
        cacc[dt] = mfma16(pa[c], vf.v, cacc[dt]);
      }
    }
    __syncthreads();
    cur ^= 1;
  }

  // ctx -> concat layout [b*S+s][h*64+d] bf16 for the output GEMM
  int h = bh & 15;
  for (int dt = 0; dt < 4; ++dt)
    for (int r = 0; r < 4; ++r) {
      int s = qbase + w * 16 + g * 4 + r;
      int d = dt * 16 + li;
      ctx[((size_t)(b * cS + s)) * cD + h * 64 + d] = f2bf(cacc[dt][r]);
    }
}

// ---------------- host launch --------------------------------------------------
extern "C" void kernel_launch(void* const* d_in, const int* in_sizes, int n_in,
                              void* d_out, int out_size, void* d_ws, size_t ws_size,
                              hipStream_t stream) {
  const float* q_in = (const float*)d_in[0];
  const float* k_in = (const float*)d_in[1];
  const float* v_in = (const float*)d_in[2];
  const float* mask = (const float*)d_in[3];
  const float* Wq = (const float*)d_in[4];
  const float* bq = (const float*)d_in[5];
  const float* Wk = (const float*)d_in[6];
  const float* bk = (const float*)d_in[7];
  const float* Wv = (const float*)d_in[8];
  const float* bv = (const float*)d_in[9];
  const float* Wo = (const float*)d_in[10];
  const float* bo = (const float*)d_in[11];

  float* out = (float*)d_out;                       // [B,S,D]
  float* attn = out + (size_t)cB * cS * cD;         // [B,H,S,S]

  // workspace layout (bf16 = 2B): 4 W^T (8MB) + Q + K + Vt + ctx (8MB ea) + flags
  const size_t MATB = (size_t)cB * cS * cD * 2;     // 8,388,608 B
  const size_t WB = (size_t)cD * cD * 2;            // 2,097,152 B
  char* ws = (char*)d_ws;
  u16* WqT = (u16*)(ws);
  u16* WkT = (u16*)(ws + WB);
  u16* WvT = (u16*)(ws + 2 * WB);
  u16* WoT = (u16*)(ws + 3 * WB);
  u16* wsQ  = (u16*)(ws + 4 * WB);
  u16* wsK  = (u16*)(ws + 4 * WB + MATB);
  u16* wsVt = (u16*)(ws + 4 * WB + 2 * MATB);
  u16* wsC  = (u16*)(ws + 4 * WB + 3 * MATB);
  unsigned char* flags = (unsigned char*)(ws + 4 * WB + 4 * MATB);
  const size_t REQUIRED = 4 * WB + 4 * MATB + 2048;
  if (ws_size < REQUIRED) return;  // loud failure (validation will catch)

  dim3 tb(32, 8);
  wt_kernel<<<dim3(32, 32), tb, 0, stream>>>(Wq, WqT);
  wt_kernel<<<dim3(32, 32), tb, 0, stream>>>(Wk, WkT);
  wt_kernel<<<dim3(32, 32), tb, 0, stream>>>(Wv, WvT);
  wt_kernel<<<dim3(32, 32), tb, 0, stream>>>(Wv, WvT);
  wt_kernel<<<dim3(32, 32), tb, 0, stream>>>(Wo, WoT);
  maskflag_kernel<<<2048, 256, 0, stream>>>(mask, flags);

  gemm128<true, false><<<256, 256, 0, stream>>>(q_in, WqT, bq, wsQ, 0.125f, 0);
  gemm128<true, false><<<256, 256, 0, stream>>>(k_in, WkT, bk, wsK, 1.0f, 0);
  gemm128<true, false><<<256, 256, 0, stream>>>(v_in, WvT, bv, wsVt, 1.0f, 1);

  attn_kernel<<<1024, 256, 0, stream>>>(wsQ, wsK, wsVt, mask, flags, attn, wsC);

  gemm128<false, true><<<256, 256, 0, stream>>>(wsC, WoT, bo, out, 1.0f, 0);
}